// Round 1
// baseline (2649.363 us; speedup 1.0000x reference)
//
#include <hip/hip_runtime.h>
#include <hip/hip_bf16.h>

typedef unsigned int uint;
typedef unsigned short u16;

#define D_ 4096
#define H_ 32
#define DH 128
#define F_ 8192
#define V_ 8192
#define S_ 1024
#define M_ 512
#define L_ 2
#define KV_ (M_ + S_)

typedef __attribute__((ext_vector_type(8))) short s16x8;
typedef __attribute__((ext_vector_type(4))) float f32x4;
typedef __attribute__((ext_vector_type(4))) u16 u16x4;

__device__ __forceinline__ u16 f2bf(float f) {
    uint u = __float_as_uint(f);
    u += 0x7FFFu + ((u >> 16) & 1u);
    return (u16)(u >> 16);
}
__device__ __forceinline__ float bf2f(u16 h) {
    return __uint_as_float(((uint)h) << 16);
}

// ---------------- embedding gather: h[row] = embed[ids[row]] ----------------
__global__ void k_embed(const int* __restrict__ ids, const float* __restrict__ embed,
                        float* __restrict__ h) {
    int row = blockIdx.x;
    const float4* src = (const float4*)(embed + (size_t)ids[row] * D_);
    float4* dst = (float4*)(h + (size_t)row * D_);
    for (int i = threadIdx.x; i < D_ / 4; i += 256) dst[i] = src[i];
}

// ---------------- RMSNorm: xb = bf16(h * rsqrt(mean(h^2)+eps) * w) ----------
__global__ __launch_bounds__(256) void k_rms(const float* __restrict__ hin,
                                             const float* __restrict__ w,
                                             u16* __restrict__ out) {
    int row = blockIdx.x, t = threadIdx.x;
    const float4* src = (const float4*)(hin + (size_t)row * D_);
    float4 v[4];
    float ss = 0.f;
#pragma unroll
    for (int i = 0; i < 4; ++i) {
        v[i] = src[t + 256 * i];
        ss += v[i].x * v[i].x + v[i].y * v[i].y + v[i].z * v[i].z + v[i].w * v[i].w;
    }
#pragma unroll
    for (int off = 32; off; off >>= 1) ss += __shfl_xor(ss, off);
    __shared__ float red[4];
    if ((t & 63) == 0) red[t >> 6] = ss;
    __syncthreads();
    float tot = red[0] + red[1] + red[2] + red[3];
    float sc = rsqrtf(tot * (1.0f / D_) + 1e-5f);
    const float4* wp = (const float4*)w;
    u16x4* op = (u16x4*)(out + (size_t)row * D_);
#pragma unroll
    for (int i = 0; i < 4; ++i) {
        float4 wv = wp[t + 256 * i];
        u16x4 o;
        o[0] = f2bf(v[i].x * sc * wv.x);
        o[1] = f2bf(v[i].y * sc * wv.y);
        o[2] = f2bf(v[i].z * sc * wv.z);
        o[3] = f2bf(v[i].w * sc * wv.w);
        op[t + 256 * i] = o;
    }
}

// ---------------- f32 -> bf16 convert (memory slab) -------------------------
__global__ void k_cvt(const float* __restrict__ src, u16* __restrict__ dst, int n4) {
    int i = blockIdx.x * 256 + threadIdx.x;
    if (i < n4) {
        float4 v = ((const float4*)src)[i];
        u16x4 o;
        o[0] = f2bf(v.x); o[1] = f2bf(v.y); o[2] = f2bf(v.z); o[3] = f2bf(v.w);
        ((u16x4*)dst)[i] = o;
    }
}

// ---------------- RoPE in-place on bf16 [rows][D], pos = pos0+row -----------
__global__ __launch_bounds__(256) void k_rope(u16* __restrict__ buf, int pos0) {
    int row = blockIdx.x, t = threadIdx.x;
    float pos = (float)(pos0 + row);
    u16* p = buf + (size_t)row * D_;
#pragma unroll
    for (int j = 0; j < 8; ++j) {
        int pid = t + 256 * j;
        int hd = pid >> 6, i = pid & 63;
        int base = hd * 128 + i;
        float invf = powf(10000.0f, -(float)i * (1.0f / 64.0f));
        float ang = pos * invf;
        float c = cosf(ang), s = sinf(ang);
        float v0 = bf2f(p[base]), v1 = bf2f(p[base + 64]);
        p[base] = f2bf(v0 * c - v1 * s);
        p[base + 64] = f2bf(v1 * c + v0 * s);
    }
}

// ---------------- transpose Vb [KV][D] -> VT [D][KV] (bf16) -----------------
__global__ __launch_bounds__(256) void k_transpose(const u16* __restrict__ src,
                                                   u16* __restrict__ dst) {
    __shared__ u16 tile[64][66];
    int tc = blockIdx.x * 64;  // D tile
    int tr = blockIdx.y * 64;  // KV tile
    int t = threadIdx.x;
    int c = t & 63, r0 = t >> 6;
#pragma unroll
    for (int i = 0; i < 16; ++i) {
        int r = r0 + i * 4;
        tile[r][c] = src[(size_t)(tr + r) * D_ + tc + c];
    }
    __syncthreads();
#pragma unroll
    for (int i = 0; i < 16; ++i) {
        int r = r0 + i * 4;
        dst[(size_t)(tc + r) * KV_ + tr + c] = tile[c][r];
    }
}

// ---------------- GEMM: C[Mr x Nn] = A(bf16) @ W(f32,[Nn][Kk])^T ------------
// 128x128 tile, BK=64, 4 waves (2x2), XOR-swizzled LDS, reg-staged with
// on-the-fly f32->bf16 conversion of W.
// EPI 0: bf16 store  1: f32 store  2: aux += acc (residual)  3: bf16(silu(aux)*acc)
template <int EPI>
__global__ __launch_bounds__(256) void k_gemm(
    const u16* __restrict__ A,
    const float* __restrict__ B0, const float* __restrict__ B1, const float* __restrict__ B2,
    void* __restrict__ O0, void* __restrict__ O1, void* __restrict__ O2,
    float* __restrict__ aux, int Nn, int Kk) {
    const float* Bw = blockIdx.z == 0 ? B0 : (blockIdx.z == 1 ? B1 : B2);
    void* Oo = blockIdx.z == 0 ? O0 : (blockIdx.z == 1 ? O1 : O2);
    __shared__ __align__(16) u16 As[128 * 64];
    __shared__ __align__(16) u16 Bs[128 * 64];
    int tid = threadIdx.x;
    int lane = tid & 63, wid = tid >> 6;
    int l16 = lane & 15, lh = lane >> 4;
    int wm = (wid >> 1) * 64, wn = (wid & 1) * 64;
    size_t bm = blockIdx.y, bn = blockIdx.x;
    f32x4 acc[4][4];
#pragma unroll
    for (int i = 0; i < 4; ++i)
#pragma unroll
        for (int j = 0; j < 4; ++j)
#pragma unroll
            for (int e = 0; e < 4; ++e) acc[i][j][e] = 0.f;

    for (int k0 = 0; k0 < Kk; k0 += 64) {
        __syncthreads();
#pragma unroll
        for (int i = 0; i < 4; ++i) {
            int c = tid + 256 * i;
            int r = c >> 3, s = c & 7;
            int sw = ((s ^ (r & 7)) * 8);
            s16x8 av = *(const s16x8*)(A + (size_t)(bm * 128 + r) * Kk + k0 + s * 8);
            *(s16x8*)(&As[r * 64 + sw]) = av;
            const float* gb = Bw + (size_t)(bn * 128 + r) * Kk + k0 + s * 8;
            float4 b0 = *(const float4*)gb;
            float4 b1 = *(const float4*)(gb + 4);
            s16x8 bv;
            bv[0] = (short)f2bf(b0.x); bv[1] = (short)f2bf(b0.y);
            bv[2] = (short)f2bf(b0.z); bv[3] = (short)f2bf(b0.w);
            bv[4] = (short)f2bf(b1.x); bv[5] = (short)f2bf(b1.y);
            bv[6] = (short)f2bf(b1.z); bv[7] = (short)f2bf(b1.w);
            *(s16x8*)(&Bs[r * 64 + sw]) = bv;
        }
        __syncthreads();
#pragma unroll
        for (int kk = 0; kk < 2; ++kk) {
            s16x8 af[4], bfr[4];
            int sidx = kk * 4 + lh;
#pragma unroll
            for (int mi = 0; mi < 4; ++mi) {
                int r = wm + mi * 16 + l16;
                af[mi] = *(const s16x8*)(&As[r * 64 + ((sidx ^ (r & 7)) * 8)]);
            }
#pragma unroll
            for (int ni = 0; ni < 4; ++ni) {
                int r = wn + ni * 16 + l16;
                bfr[ni] = *(const s16x8*)(&Bs[r * 64 + ((sidx ^ (r & 7)) * 8)]);
            }
#pragma unroll
            for (int mi = 0; mi < 4; ++mi)
#pragma unroll
                for (int ni = 0; ni < 4; ++ni)
                    acc[mi][ni] = __builtin_amdgcn_mfma_f32_16x16x32_bf16(
                        af[mi], bfr[ni], acc[mi][ni], 0, 0, 0);
        }
    }
    // epilogue: D layout col = lane&15, row = (lane>>4)*4 + r
#pragma unroll
    for (int mi = 0; mi < 4; ++mi) {
#pragma unroll
        for (int ni = 0; ni < 4; ++ni) {
#pragma unroll
            for (int r = 0; r < 4; ++r) {
                int grow = (int)bm * 128 + wm + mi * 16 + lh * 4 + r;
                int gcol = (int)bn * 128 + wn + ni * 16 + l16;
                size_t idx = (size_t)grow * Nn + gcol;
                float vv = acc[mi][ni][r];
                if (EPI == 0) {
                    ((u16*)Oo)[idx] = f2bf(vv);
                } else if (EPI == 1) {
                    ((float*)Oo)[idx] = vv;
                } else if (EPI == 2) {
                    aux[idx] += vv;
                } else {
                    float g = aux[idx];
                    float sg = g / (1.0f + __expf(-g));
                    ((u16*)Oo)[idx] = f2bf(sg * vv);
                }
            }
        }
    }
}

// ---------------- flash attention: 1 wave per (16 q-rows, head) -------------
// Qb/Kb bf16 [rows][D] (post-RoPE), VT bf16 [D][KV], Ob bf16 [S][D]
__global__ __launch_bounds__(64) void k_attn(const u16* __restrict__ Qb,
                                             const u16* __restrict__ Kb,
                                             const u16* __restrict__ VT,
                                             u16* __restrict__ Ob) {
    int qt = blockIdx.x, hd = blockIdx.y;
    int lane = threadIdx.x, l16 = lane & 15, lh = lane >> 4;
    __shared__ __align__(16) float Pl[16 * 36];  // padded stride 36 floats

    s16x8 qf[4];
#pragma unroll
    for (int c = 0; c < 4; ++c)
        qf[c] = *(const s16x8*)(Qb + (size_t)(qt * 16 + l16) * D_ + hd * DH + c * 32 + lh * 8);

    f32x4 o[8];
#pragma unroll
    for (int dc = 0; dc < 8; ++dc)
#pragma unroll
        for (int e = 0; e < 4; ++e) o[dc][e] = 0.f;
    float m[4], lsum[4];
#pragma unroll
    for (int r = 0; r < 4; ++r) { m[r] = -1e30f; lsum[r] = 0.f; }

    const float scale = 0.08838834764831845f;  // 1/sqrt(128)
    int qbase = M_ + qt * 16;
    int nkb = (M_ + qt * 16 + 16 + 31) >> 5;

    for (int kb = 0; kb < nkb; ++kb) {
        f32x4 s0, s1;
#pragma unroll
        for (int e = 0; e < 4; ++e) { s0[e] = 0.f; s1[e] = 0.f; }
#pragma unroll
        for (int c = 0; c < 4; ++c) {
            s16x8 kf0 = *(const s16x8*)(Kb + (size_t)(kb * 32 + l16) * D_ + hd * DH + c * 32 + lh * 8);
            s16x8 kf1 = *(const s16x8*)(Kb + (size_t)(kb * 32 + 16 + l16) * D_ + hd * DH + c * 32 + lh * 8);
            s0 = __builtin_amdgcn_mfma_f32_16x16x32_bf16(qf[c], kf0, s0, 0, 0, 0);
            s1 = __builtin_amdgcn_mfma_f32_16x16x32_bf16(qf[c], kf1, s1, 0, 0, 0);
        }
        int kp0 = kb * 32 + l16, kp1 = kp0 + 16;
        float pm[4];
#pragma unroll
        for (int r = 0; r < 4; ++r) {
            int qp = qbase + lh * 4 + r;
            float v0 = s0[r] * scale; if (kp0 > qp) v0 = -1e30f;
            float v1 = s1[r] * scale; if (kp1 > qp) v1 = -1e30f;
            s0[r] = v0; s1[r] = v1;
            pm[r] = fmaxf(v0, v1);
        }
#pragma unroll
        for (int r = 0; r < 4; ++r) {
#pragma unroll
            for (int off = 8; off; off >>= 1) pm[r] = fmaxf(pm[r], __shfl_xor(pm[r], off));
        }
        float alpha[4];
#pragma unroll
        for (int r = 0; r < 4; ++r) {
            float mn = fmaxf(m[r], pm[r]);
            alpha[r] = __expf(m[r] - mn);
            m[r] = mn;
            float p0 = __expf(s0[r] - mn), p1 = __expf(s1[r] - mn);
            s0[r] = p0; s1[r] = p1;
            float t = p0 + p1;
#pragma unroll
            for (int off = 8; off; off >>= 1) t += __shfl_xor(t, off);
            lsum[r] = lsum[r] * alpha[r] + t;
        }
        // transpose P via LDS: write D-layout, read A-layout
#pragma unroll
        for (int r = 0; r < 4; ++r) {
            Pl[(lh * 4 + r) * 36 + l16] = s0[r];
            Pl[(lh * 4 + r) * 36 + 16 + l16] = s1[r];
        }
        __syncthreads();
        s16x8 pf;
        {
            const f32x4* pp = (const f32x4*)(Pl + l16 * 36 + lh * 8);
            f32x4 a = pp[0], b = pp[1];
            pf[0] = (short)f2bf(a[0]); pf[1] = (short)f2bf(a[1]);
            pf[2] = (short)f2bf(a[2]); pf[3] = (short)f2bf(a[3]);
            pf[4] = (short)f2bf(b[0]); pf[5] = (short)f2bf(b[1]);
            pf[6] = (short)f2bf(b[2]); pf[7] = (short)f2bf(b[3]);
        }
        __syncthreads();
#pragma unroll
        for (int dc = 0; dc < 8; ++dc) {
#pragma unroll
            for (int r = 0; r < 4; ++r) o[dc][r] *= alpha[r];
        }
#pragma unroll
        for (int dc = 0; dc < 8; ++dc) {
            s16x8 vf = *(const s16x8*)(VT + (size_t)(hd * DH + dc * 16 + l16) * KV_ + kb * 32 + lh * 8);
            o[dc] = __builtin_amdgcn_mfma_f32_16x16x32_bf16(pf, vf, o[dc], 0, 0, 0);
        }
    }
#pragma unroll
    for (int dc = 0; dc < 8; ++dc) {
#pragma unroll
        for (int r = 0; r < 4; ++r) {
            float val = o[dc][r] / lsum[r];
            Ob[(size_t)(qt * 16 + lh * 4 + r) * D_ + hd * DH + dc * 16 + l16] = f2bf(val);
        }
    }
}

// ---------------- launch ----------------------------------------------------
extern "C" void kernel_launch(void* const* d_in, const int* in_sizes, int n_in,
                              void* d_out, int out_size, void* d_ws, size_t ws_size,
                              hipStream_t stream) {
    const int* ids = (const int*)d_in[0];
    const float* memory = (const float*)d_in[1];
    const float* embed = (const float*)d_in[2];
    const float* Wq = (const float*)d_in[3];
    const float* Wk = (const float*)d_in[4];
    const float* Wv = (const float*)d_in[5];
    const float* Wo = (const float*)d_in[6];
    const float* Wg = (const float*)d_in[7];
    const float* Wu = (const float*)d_in[8];
    const float* Wd = (const float*)d_in[9];
    const float* Wmk = (const float*)d_in[10];
    const float* Wmv = (const float*)d_in[11];
    const float* ln1 = (const float*)d_in[12];
    const float* ln2 = (const float*)d_in[13];
    const float* normw = (const float*)d_in[14];
    const float* lm = (const float*)d_in[15];

    char* ws = (char*)d_ws;
    float* h   = (float*)(ws + 0);            // 16.78 MB f32 [S][D]
    u16* xb    = (u16*)(ws + 16777216);       // 8.39 MB bf16 [S][D]
    u16* Qb    = (u16*)(ws + 25165824);       // 8.39 MB
    u16* Kb    = (u16*)(ws + 33554432);       // 12.58 MB [KV][D]
    u16* Vb    = (u16*)(ws + 46137344);       // 12.58 MB
    u16* VT    = (u16*)(ws + 58720256);       // 12.58 MB [D][KV]
    u16* Ob    = (u16*)(ws + 71303168);       // 8.39 MB
    u16* memb  = (u16*)(ws + 79691776);       // 4.19 MB [M][D]
    float* Gbuf = (float*)(ws + 25165824);    // 33.55 MB f32 [S][F] (overlaps dead Q/K/V)
    u16* tb    = (u16*)(ws + 58720256);       // 16.78 MB bf16 [S][F] (overlaps dead VT/Ob)
    // total footprint: 80 MB

    k_embed<<<S_, 256, 0, stream>>>(ids, embed, h);

    for (int l = 0; l < L_; ++l) {
        k_rms<<<S_, 256, 0, stream>>>(h, ln1 + l * D_, xb);
        k_cvt<<<(M_ * D_ / 4 + 255) / 256, 256, 0, stream>>>(memory + (size_t)l * M_ * D_, memb, M_ * D_ / 4);
        // fused Q/K/V projections (z selects weight & output)
        k_gemm<0><<<dim3(D_ / 128, S_ / 128, 3), 256, 0, stream>>>(
            xb, Wq + (size_t)l * D_ * D_, Wk + (size_t)l * D_ * D_, Wv + (size_t)l * D_ * D_,
            Qb, Kb + (size_t)M_ * D_, Vb + (size_t)M_ * D_, nullptr, D_, D_);
        // memory K/V projections into rows 0..M-1
        k_gemm<0><<<dim3(D_ / 128, M_ / 128, 2), 256, 0, stream>>>(
            memb, Wmk + (size_t)l * D_ * D_, Wmv + (size_t)l * D_ * D_, nullptr,
            Kb, Vb, nullptr, nullptr, D_, D_);
        k_rope<<<S_, 256, 0, stream>>>(Qb, M_);
        k_rope<<<KV_, 256, 0, stream>>>(Kb, 0);
        k_transpose<<<dim3(D_ / 64, KV_ / 64), 256, 0, stream>>>(Vb, VT);
        k_attn<<<dim3(S_ / 16, H_), 64, 0, stream>>>(Qb, Kb, VT, Ob);
        // h += Ob @ Wo^T
        k_gemm<2><<<dim3(D_ / 128, S_ / 128, 1), 256, 0, stream>>>(
            Ob, Wo + (size_t)l * D_ * D_, nullptr, nullptr,
            nullptr, nullptr, nullptr, h, D_, D_);
        // FFN
        k_rms<<<S_, 256, 0, stream>>>(h, ln2 + l * D_, xb);
        k_gemm<1><<<dim3(F_ / 128, S_ / 128, 1), 256, 0, stream>>>(
            xb, Wg + (size_t)l * F_ * D_, nullptr, nullptr,
            Gbuf, nullptr, nullptr, nullptr, F_, D_);
        k_gemm<3><<<dim3(F_ / 128, S_ / 128, 1), 256, 0, stream>>>(
            xb, Wu + (size_t)l * F_ * D_, nullptr, nullptr,
            tb, nullptr, nullptr, Gbuf, F_, D_);
        k_gemm<2><<<dim3(D_ / 128, S_ / 128, 1), 256, 0, stream>>>(
            tb, Wd + (size_t)l * D_ * F_, nullptr, nullptr,
            nullptr, nullptr, nullptr, h, D_, F_);
    }
    k_rms<<<S_, 256, 0, stream>>>(h, normw, xb);
    k_gemm<1><<<dim3(V_ / 128, S_ / 128, 1), 256, 0, stream>>>(
        xb, lm, nullptr, nullptr, (float*)d_out, nullptr, nullptr, nullptr, V_, D_);
}

// Round 2
// 1862.764 us; speedup vs baseline: 1.4223x; 1.4223x over previous
//
#include <hip/hip_runtime.h>
#include <hip/hip_bf16.h>

typedef unsigned int uint;
typedef unsigned short u16;

#define D_ 4096
#define H_ 32
#define DH 128
#define F_ 8192
#define V_ 8192
#define S_ 1024
#define M_ 512
#define L_ 2
#define KV_ (M_ + S_)

typedef __attribute__((ext_vector_type(8))) short s16x8;
typedef __attribute__((ext_vector_type(4))) float f32x4;
typedef __attribute__((ext_vector_type(4))) u16 u16x4;

__device__ __forceinline__ u16 f2bf(float f) {
    uint u = __float_as_uint(f);
    u += 0x7FFFu + ((u >> 16) & 1u);
    return (u16)(u >> 16);
}
__device__ __forceinline__ float bf2f(u16 h) {
    return __uint_as_float(((uint)h) << 16);
}
__device__ __forceinline__ uint cvt_pk_bf16(float a, float b) {
    uint r;
    asm volatile("v_cvt_pk_bf16_f32 %0, %1, %2" : "=v"(r) : "v"(a), "v"(b));
    return r;
}
__device__ __forceinline__ void gload_lds16(const void* g, void* l) {
    __builtin_amdgcn_global_load_lds(
        (const __attribute__((address_space(1))) unsigned int*)g,
        (__attribute__((address_space(3))) unsigned int*)l, 16, 0, 0);
}

// ---------------- embedding gather ------------------------------------------
__global__ void k_embed(const int* __restrict__ ids, const float* __restrict__ embed,
                        float* __restrict__ h) {
    int row = blockIdx.x;
    const float4* src = (const float4*)(embed + (size_t)ids[row] * D_);
    float4* dst = (float4*)(h + (size_t)row * D_);
    for (int i = threadIdx.x; i < D_ / 4; i += 256) dst[i] = src[i];
}

// ---------------- RMSNorm ---------------------------------------------------
__global__ __launch_bounds__(256) void k_rms(const float* __restrict__ hin,
                                             const float* __restrict__ w,
                                             u16* __restrict__ out) {
    int row = blockIdx.x, t = threadIdx.x;
    const float4* src = (const float4*)(hin + (size_t)row * D_);
    float4 v[4];
    float ss = 0.f;
#pragma unroll
    for (int i = 0; i < 4; ++i) {
        v[i] = src[t + 256 * i];
        ss += v[i].x * v[i].x + v[i].y * v[i].y + v[i].z * v[i].z + v[i].w * v[i].w;
    }
#pragma unroll
    for (int off = 32; off; off >>= 1) ss += __shfl_xor(ss, off);
    __shared__ float red[4];
    if ((t & 63) == 0) red[t >> 6] = ss;
    __syncthreads();
    float tot = red[0] + red[1] + red[2] + red[3];
    float sc = rsqrtf(tot * (1.0f / D_) + 1e-5f);
    const float4* wp = (const float4*)w;
    u16x4* op = (u16x4*)(out + (size_t)row * D_);
#pragma unroll
    for (int i = 0; i < 4; ++i) {
        float4 wv = wp[t + 256 * i];
        u16x4 o;
        o[0] = f2bf(v[i].x * sc * wv.x);
        o[1] = f2bf(v[i].y * sc * wv.y);
        o[2] = f2bf(v[i].z * sc * wv.z);
        o[3] = f2bf(v[i].w * sc * wv.w);
        op[t + 256 * i] = o;
    }
}

// ---------------- f32 -> bf16 convert ---------------------------------------
__global__ void k_cvt(const float* __restrict__ src, u16* __restrict__ dst, int n4) {
    int i = blockIdx.x * 256 + threadIdx.x;
    if (i < n4) {
        float4 v = ((const float4*)src)[i];
        u16x4 o;
        o[0] = f2bf(v.x); o[1] = f2bf(v.y); o[2] = f2bf(v.z); o[3] = f2bf(v.w);
        ((u16x4*)dst)[i] = o;
    }
}

// ---------------- RoPE cos/sin table: tab[pos][i] = {cos, sin} --------------
__global__ void k_ropetab(float* __restrict__ tab) {
    int pos = blockIdx.x, i = threadIdx.x;  // 64 threads
    float invf = powf(10000.0f, -(float)i * (1.0f / 64.0f));
    float ang = (float)pos * invf;
    tab[(size_t)pos * 128 + i * 2] = cosf(ang);
    tab[(size_t)pos * 128 + i * 2 + 1] = sinf(ang);
}

// ---------------- RoPE in-place (table-driven) ------------------------------
__global__ __launch_bounds__(256) void k_rope(u16* __restrict__ buf,
                                              const float* __restrict__ tab, int pos0) {
    int row = blockIdx.x, t = threadIdx.x;
    const float2* tp = (const float2*)(tab + (size_t)(pos0 + row) * 128);
    u16* p = buf + (size_t)row * D_;
#pragma unroll
    for (int j = 0; j < 8; ++j) {
        int pid = t + 256 * j;
        int hd = pid >> 6, i = pid & 63;
        float2 cs = tp[i];
        int base = hd * 128 + i;
        float v0 = bf2f(p[base]), v1 = bf2f(p[base + 64]);
        p[base] = f2bf(v0 * cs.x - v1 * cs.y);
        p[base + 64] = f2bf(v1 * cs.x + v0 * cs.y);
    }
}

// ---------------- transpose Vb [KV][D] -> VT [D][KV] ------------------------
__global__ __launch_bounds__(256) void k_transpose(const u16* __restrict__ src,
                                                   u16* __restrict__ dst) {
    __shared__ u16 tile[64][66];
    int tc = blockIdx.x * 64;
    int tr = blockIdx.y * 64;
    int t = threadIdx.x;
    int c = t & 63, r0 = t >> 6;
#pragma unroll
    for (int i = 0; i < 16; ++i) {
        int r = r0 + i * 4;
        tile[r][c] = src[(size_t)(tr + r) * D_ + tc + c];
    }
    __syncthreads();
#pragma unroll
    for (int i = 0; i < 16; ++i) {
        int r = r0 + i * 4;
        dst[(size_t)(tc + r) * KV_ + tr + c] = tile[c][r];
    }
}

// ---------------- batched pipelined GEMM ------------------------------------
// C[mrows x Nn] = A(bf16) @ W(f32 [Nn][Kfull])^T   (per z-slice)
// 128x128 tile, BK=64, 4 waves 2x2. A: global_load_lds -> linear LDS.
// B: reg-staged (issue-early), v_cvt_pk_bf16_f32, XOR-swizzled LDS.
// Double-buffered, one barrier per K-step (T3-minimum 2-phase).
// EPI 0: bf16 store  1: f32 store  3: bf16(silu(aux)*acc)  4: atomicAdd f32
struct GemmBatch {
    const u16* A[5];
    const float* B[5];
    void* O[5];
    int mrows[5];
    int koff[5];
    float* aux;
};

template <int EPI>
__global__ __launch_bounds__(256) void k_gemm(GemmBatch P, int Nn, int Kstep, int Kfull) {
    int z = blockIdx.z;
    size_t bm = blockIdx.y, bn = blockIdx.x;
    if ((int)(bm * 128) >= P.mrows[z]) return;
    const u16* A = P.A[z];
    const float* Bw = P.B[z];
    int koff = P.koff[z];

    __shared__ __align__(16) u16 As[2][128 * 64];
    __shared__ __align__(16) u16 Bs[2][128 * 64];
    int tid = threadIdx.x;
    int lane = tid & 63, wid = tid >> 6;
    int l16 = lane & 15, lh = lane >> 4;
    int wm = (wid >> 1) * 64, wn = (wid & 1) * 64;

    const u16* pA[4];
    const float* pB[4];
    int ldsAo[4], bso[4];
#pragma unroll
    for (int i = 0; i < 4; ++i) {
        int c = tid + 256 * i;
        int r = c >> 3, s = c & 7;
        pA[i] = A + (size_t)(bm * 128 + r) * Kfull + koff + s * 8;
        pB[i] = Bw + (size_t)(bn * 128 + r) * Kfull + koff + s * 8;
        ldsAo[i] = c * 8;                      // u16 elements
        bso[i] = r * 64 + ((s ^ (r & 7)) * 8); // swizzled u16 elements
    }

    f32x4 acc[4][4];
#pragma unroll
    for (int i = 0; i < 4; ++i)
#pragma unroll
        for (int j = 0; j < 4; ++j)
#pragma unroll
            for (int e = 0; e < 4; ++e) acc[i][j][e] = 0.f;

    float4 br[8];
    auto issueA = [&](int p, int k0) {
#pragma unroll
        for (int i = 0; i < 4; ++i)
            gload_lds16(pA[i] + k0, &As[p][0] + ldsAo[i]);
    };
    auto issueB = [&](int k0) {
#pragma unroll
        for (int i = 0; i < 4; ++i) {
            br[2 * i] = *(const float4*)(pB[i] + k0);
            br[2 * i + 1] = *(const float4*)(pB[i] + k0 + 4);
        }
    };
    auto cvtwrite = [&](int p) {
#pragma unroll
        for (int i = 0; i < 4; ++i) {
            uint4 w;
            w.x = cvt_pk_bf16(br[2 * i].x, br[2 * i].y);
            w.y = cvt_pk_bf16(br[2 * i].z, br[2 * i].w);
            w.z = cvt_pk_bf16(br[2 * i + 1].x, br[2 * i + 1].y);
            w.w = cvt_pk_bf16(br[2 * i + 1].z, br[2 * i + 1].w);
            *(uint4*)(&Bs[p][bso[i]]) = w;
        }
    };
    auto compute = [&](int p) {
#pragma unroll
        for (int kk = 0; kk < 2; ++kk) {
            int sidx = kk * 4 + lh;
            s16x8 af[4], bf4[4];
#pragma unroll
            for (int mi = 0; mi < 4; ++mi)
                af[mi] = *(const s16x8*)(&As[p][(wm + mi * 16 + l16) * 64 + sidx * 8]);
#pragma unroll
            for (int ni = 0; ni < 4; ++ni) {
                int r = wn + ni * 16 + l16;
                bf4[ni] = *(const s16x8*)(&Bs[p][r * 64 + ((sidx ^ (r & 7)) * 8)]);
            }
#pragma unroll
            for (int mi = 0; mi < 4; ++mi)
#pragma unroll
                for (int ni = 0; ni < 4; ++ni)
                    acc[mi][ni] = __builtin_amdgcn_mfma_f32_16x16x32_bf16(
                        af[mi], bf4[ni], acc[mi][ni], 0, 0, 0);
        }
    };

    int nt = Kstep >> 6;
    issueA(0, 0);
    issueB(0);
    cvtwrite(0);
    __syncthreads();
    int p = 0;
    for (int t = 0; t < nt; ++t) {
        bool pre = (t + 1 < nt);
        if (pre) {
            issueA(p ^ 1, (t + 1) << 6);
            issueB((t + 1) << 6);
        }
        compute(p);
        if (pre) cvtwrite(p ^ 1);
        __syncthreads();
        p ^= 1;
    }

    void* Oo = P.O[z];
#pragma unroll
    for (int mi = 0; mi < 4; ++mi) {
#pragma unroll
        for (int ni = 0; ni < 4; ++ni) {
#pragma unroll
            for (int r = 0; r < 4; ++r) {
                int grow = (int)bm * 128 + wm + mi * 16 + lh * 4 + r;
                int gcol = (int)bn * 128 + wn + ni * 16 + l16;
                size_t idx = (size_t)grow * Nn + gcol;
                float v = acc[mi][ni][r];
                if constexpr (EPI == 0) {
                    ((u16*)Oo)[idx] = f2bf(v);
                } else if constexpr (EPI == 1) {
                    ((float*)Oo)[idx] = v;
                } else if constexpr (EPI == 3) {
                    float g = P.aux[idx];
                    float sg = g / (1.0f + __expf(-g));
                    ((u16*)Oo)[idx] = f2bf(sg * v);
                } else {
                    atomicAdd((float*)Oo + idx, v);
                }
            }
        }
    }
}

// ---------------- flash attention: 1 wave per (16 q-rows, head) -------------
__global__ __launch_bounds__(64) void k_attn(const u16* __restrict__ Qb,
                                             const u16* __restrict__ Kb,
                                             const u16* __restrict__ VT,
                                             u16* __restrict__ Ob) {
    int qt = blockIdx.x, hd = blockIdx.y;
    int lane = threadIdx.x, l16 = lane & 15, lh = lane >> 4;
    __shared__ __align__(16) float Pl[16 * 36];

    s16x8 qf[4];
#pragma unroll
    for (int c = 0; c < 4; ++c)
        qf[c] = *(const s16x8*)(Qb + (size_t)(qt * 16 + l16) * D_ + hd * DH + c * 32 + lh * 8);

    f32x4 o[8];
#pragma unroll
    for (int dc = 0; dc < 8; ++dc)
#pragma unroll
        for (int e = 0; e < 4; ++e) o[dc][e] = 0.f;
    float m[4], lsum[4];
#pragma unroll
    for (int r = 0; r < 4; ++r) { m[r] = -1e30f; lsum[r] = 0.f; }

    const float scale = 0.08838834764831845f;
    int qbase = M_ + qt * 16;
    int nkb = (M_ + qt * 16 + 16 + 31) >> 5;

    for (int kb = 0; kb < nkb; ++kb) {
        f32x4 s0, s1;
#pragma unroll
        for (int e = 0; e < 4; ++e) { s0[e] = 0.f; s1[e] = 0.f; }
#pragma unroll
        for (int c = 0; c < 4; ++c) {
            s16x8 kf0 = *(const s16x8*)(Kb + (size_t)(kb * 32 + l16) * D_ + hd * DH + c * 32 + lh * 8);
            s16x8 kf1 = *(const s16x8*)(Kb + (size_t)(kb * 32 + 16 + l16) * D_ + hd * DH + c * 32 + lh * 8);
            s0 = __builtin_amdgcn_mfma_f32_16x16x32_bf16(qf[c], kf0, s0, 0, 0, 0);
            s1 = __builtin_amdgcn_mfma_f32_16x16x32_bf16(qf[c], kf1, s1, 0, 0, 0);
        }
        int kp0 = kb * 32 + l16, kp1 = kp0 + 16;
        float pm[4];
#pragma unroll
        for (int r = 0; r < 4; ++r) {
            int qp = qbase + lh * 4 + r;
            float v0 = s0[r] * scale; if (kp0 > qp) v0 = -1e30f;
            float v1 = s1[r] * scale; if (kp1 > qp) v1 = -1e30f;
            s0[r] = v0; s1[r] = v1;
            pm[r] = fmaxf(v0, v1);
        }
#pragma unroll
        for (int r = 0; r < 4; ++r) {
#pragma unroll
            for (int off = 8; off; off >>= 1) pm[r] = fmaxf(pm[r], __shfl_xor(pm[r], off));
        }
        float alpha[4];
#pragma unroll
        for (int r = 0; r < 4; ++r) {
            float mn = fmaxf(m[r], pm[r]);
            alpha[r] = __expf(m[r] - mn);
            m[r] = mn;
            float p0 = __expf(s0[r] - mn), p1 = __expf(s1[r] - mn);
            s0[r] = p0; s1[r] = p1;
            float t = p0 + p1;
#pragma unroll
            for (int off = 8; off; off >>= 1) t += __shfl_xor(t, off);
            lsum[r] = lsum[r] * alpha[r] + t;
        }
#pragma unroll
        for (int r = 0; r < 4; ++r) {
            Pl[(lh * 4 + r) * 36 + l16] = s0[r];
            Pl[(lh * 4 + r) * 36 + 16 + l16] = s1[r];
        }
        __syncthreads();
        s16x8 pf;
        {
            const f32x4* pp = (const f32x4*)(Pl + l16 * 36 + lh * 8);
            f32x4 a = pp[0], b = pp[1];
            pf[0] = (short)f2bf(a[0]); pf[1] = (short)f2bf(a[1]);
            pf[2] = (short)f2bf(a[2]); pf[3] = (short)f2bf(a[3]);
            pf[4] = (short)f2bf(b[0]); pf[5] = (short)f2bf(b[1]);
            pf[6] = (short)f2bf(b[2]); pf[7] = (short)f2bf(b[3]);
        }
        __syncthreads();
#pragma unroll
        for (int dc = 0; dc < 8; ++dc) {
#pragma unroll
            for (int r = 0; r < 4; ++r) o[dc][r] *= alpha[r];
        }
#pragma unroll
        for (int dc = 0; dc < 8; ++dc) {
            s16x8 vf = *(const s16x8*)(VT + (size_t)(hd * DH + dc * 16 + l16) * KV_ + kb * 32 + lh * 8);
            o[dc] = __builtin_amdgcn_mfma_f32_16x16x32_bf16(pf, vf, o[dc], 0, 0, 0);
        }
    }
#pragma unroll
    for (int dc = 0; dc < 8; ++dc) {
#pragma unroll
        for (int r = 0; r < 4; ++r) {
            float val = o[dc][r] / lsum[r];
            Ob[(size_t)(qt * 16 + lh * 4 + r) * D_ + hd * DH + dc * 16 + l16] = f2bf(val);
        }
    }
}

// ---------------- launch ----------------------------------------------------
extern "C" void kernel_launch(void* const* d_in, const int* in_sizes, int n_in,
                              void* d_out, int out_size, void* d_ws, size_t ws_size,
                              hipStream_t stream) {
    const int* ids = (const int*)d_in[0];
    const float* memory = (const float*)d_in[1];
    const float* embed = (const float*)d_in[2];
    const float* Wq = (const float*)d_in[3];
    const float* Wk = (const float*)d_in[4];
    const float* Wv = (const float*)d_in[5];
    const float* Wo = (const float*)d_in[6];
    const float* Wg = (const float*)d_in[7];
    const float* Wu = (const float*)d_in[8];
    const float* Wd = (const float*)d_in[9];
    const float* Wmk = (const float*)d_in[10];
    const float* Wmv = (const float*)d_in[11];
    const float* ln1 = (const float*)d_in[12];
    const float* ln2 = (const float*)d_in[13];
    const float* normw = (const float*)d_in[14];
    const float* lm = (const float*)d_in[15];

    char* ws = (char*)d_ws;
    float* h   = (float*)(ws + 0x0000000);   // 16.78 MB f32 [S][D]
    u16* xb    = (u16*)(ws + 0x1000000);     // 8.39 MB bf16 [S][D]
    float* tab = (float*)(ws + 0x1800000);   // 0.79 MB f32 [KV][128]
    u16* memb  = (u16*)(ws + 0x1900000);     // 4.19 MB bf16 [M][D]
    u16* Qb    = (u16*)(ws + 0x1E00000);     // 8.39 MB
    u16* Kb    = (u16*)(ws + 0x2600000);     // 12.58 MB [KV][D]
    u16* Vb    = (u16*)(ws + 0x3200000);     // 12.58 MB
    u16* VT    = (u16*)(ws + 0x3E00000);     // 12.58 MB [D][KV]
    u16* Ob    = (u16*)(ws + 0x4A00000);     // 8.39 MB -> end 0x5200000 (86 MB)
    // FFN-phase overlays (Qb/Kb/Vb/VT/Ob dead by then):
    float* Gbuf = (float*)(ws + 0x1E00000);  // 33.55 MB f32 [S][F]
    u16* tb     = (u16*)(ws + 0x3E00000);    // 16.78 MB bf16 [S][F]

    k_embed<<<S_, 256, 0, stream>>>(ids, embed, h);
    k_ropetab<<<KV_, 64, 0, stream>>>(tab);

    for (int l = 0; l < L_; ++l) {
        const float* Wq_l = Wq + (size_t)l * D_ * D_;
        const float* Wk_l = Wk + (size_t)l * D_ * D_;
        const float* Wv_l = Wv + (size_t)l * D_ * D_;
        const float* Wo_l = Wo + (size_t)l * D_ * D_;
        const float* Wmk_l = Wmk + (size_t)l * D_ * D_;
        const float* Wmv_l = Wmv + (size_t)l * D_ * D_;
        const float* Wg_l = Wg + (size_t)l * (size_t)F_ * D_;
        const float* Wu_l = Wu + (size_t)l * (size_t)F_ * D_;
        const float* Wd_l = Wd + (size_t)l * (size_t)D_ * F_;

        k_rms<<<S_, 256, 0, stream>>>(h, ln1 + l * D_, xb);
        k_cvt<<<(M_ * D_ / 4 + 255) / 256, 256, 0, stream>>>(
            memory + (size_t)l * M_ * D_, memb, M_ * D_ / 4);

        // QKV + memory-KV fused: 5 z-slices, 1280 active blocks
        GemmBatch g1{};
        g1.A[0] = xb;   g1.B[0] = Wq_l;  g1.O[0] = Qb;                    g1.mrows[0] = S_;
        g1.A[1] = xb;   g1.B[1] = Wk_l;  g1.O[1] = Kb + (size_t)M_ * D_;  g1.mrows[1] = S_;
        g1.A[2] = xb;   g1.B[2] = Wv_l;  g1.O[2] = Vb + (size_t)M_ * D_;  g1.mrows[2] = S_;
        g1.A[3] = memb; g1.B[3] = Wmk_l; g1.O[3] = Kb;                    g1.mrows[3] = M_;
        g1.A[4] = memb; g1.B[4] = Wmv_l; g1.O[4] = Vb;                    g1.mrows[4] = M_;
        k_gemm<0><<<dim3(D_ / 128, S_ / 128, 5), 256, 0, stream>>>(g1, D_, D_, D_);

        k_rope<<<S_, 256, 0, stream>>>(Qb, tab, M_);
        k_rope<<<KV_, 256, 0, stream>>>(Kb, tab, 0);
        k_transpose<<<dim3(D_ / 64, KV_ / 64), 256, 0, stream>>>(Vb, VT);
        k_attn<<<dim3(S_ / 16, H_), 64, 0, stream>>>(Qb, Kb, VT, Ob);

        // h += Ob @ Wo^T  (split-K=2, atomic residual)
        GemmBatch g2{};
        g2.A[0] = Ob; g2.B[0] = Wo_l; g2.O[0] = h; g2.mrows[0] = S_; g2.koff[0] = 0;
        g2.A[1] = Ob; g2.B[1] = Wo_l; g2.O[1] = h; g2.mrows[1] = S_; g2.koff[1] = 2048;
        k_gemm<4><<<dim3(D_ / 128, S_ / 128, 2), 256, 0, stream>>>(g2, D_, 2048, D_);

        // FFN
        k_rms<<<S_, 256, 0, stream>>>(h, ln2 + l * D_, xb);
        GemmBatch g3{};
        g3.A[0] = xb; g3.B[0] = Wg_l; g3.O[0] = Gbuf; g3.mrows[0] = S_;
        k_gemm<1><<<dim3(F_ / 128, S_ / 128, 1), 256, 0, stream>>>(g3, F_, D_, D_);
        GemmBatch g4{};
        g4.A[0] = xb; g4.B[0] = Wu_l; g4.O[0] = tb; g4.mrows[0] = S_; g4.aux = Gbuf;
        k_gemm<3><<<dim3(F_ / 128, S_ / 128, 1), 256, 0, stream>>>(g4, F_, D_, D_);
        GemmBatch g5{};
        g5.A[0] = tb; g5.B[0] = Wd_l; g5.O[0] = h; g5.mrows[0] = S_; g5.koff[0] = 0;
        g5.A[1] = tb; g5.B[1] = Wd_l; g5.O[1] = h; g5.mrows[1] = S_; g5.koff[1] = 4096;
        k_gemm<4><<<dim3(D_ / 128, S_ / 128, 2), 256, 0, stream>>>(g5, D_, 4096, F_);
    }

    k_rms<<<S_, 256, 0, stream>>>(h, normw, xb);
    GemmBatch g6{};
    g6.A[0] = xb; g6.B[0] = lm; g6.O[0] = (float*)d_out; g6.mrows[0] = S_;
    k_gemm<1><<<dim3(V_ / 128, S_ / 128, 1), 256, 0, stream>>>(g6, V_, D_, D_);
}